// Round 3
// baseline (191.977 us; speedup 1.0000x reference)
//
#include <hip/hip_runtime.h>

#define N_RAYS 65536
#define N_PTS 128
#define FEAT 3
#define FAR_DELTA 1e10f
#define RAYS_PER_BLOCK 16

// Direct global->LDS staging (bypasses vL1D, which R1/R2 showed caps delivered
// read BW at ~4.5 B/cyc/CU), then R2's verified 4-rays-per-wave compute core
// reading from LDS.
__device__ __forceinline__ void load_lds16(const void* g, void* l) {
    __builtin_amdgcn_global_load_lds(
        (const __attribute__((address_space(1))) void*)g,
        (__attribute__((address_space(3))) void*)l, 16, 0, 0);
}

__global__ __launch_bounds__(256) void volrend_kernel(
    const float* __restrict__ depth,
    const float* __restrict__ density,
    const float* __restrict__ feature,
    float* __restrict__ out)
{
    __shared__ alignas(16) float s_depth  [RAYS_PER_BLOCK * N_PTS];        // 8 KB
    __shared__ alignas(16) float s_density[RAYS_PER_BLOCK * N_PTS];        // 8 KB
    __shared__ alignas(16) float s_feat   [RAYS_PER_BLOCK * N_PTS * FEAT]; // 24 KB

    const int tid = threadIdx.x;
    const int wv  = tid >> 6;      // wave in block (0..3)
    const int ln  = tid & 63;      // lane
    const int base_ray = blockIdx.x * RAYS_PER_BLOCK;

    // ---- stage: three contiguous global regions -> LDS, 1 KB per wave-instr ----
    const char* gd = (const char*)(depth   + (size_t)base_ray * N_PTS);
    const char* gr = (const char*)(density + (size_t)base_ray * N_PTS);
    const char* gf = (const char*)(feature + (size_t)base_ray * N_PTS * FEAT);
    const int lane_off = ln * 16;

    #pragma unroll
    for (int it = 0; it < 2; ++it) {          // 8 KB depth
        int off = (it * 4 + wv) * 1024;
        load_lds16(gd + off + lane_off, (char*)s_depth + off);
    }
    #pragma unroll
    for (int it = 0; it < 2; ++it) {          // 8 KB density
        int off = (it * 4 + wv) * 1024;
        load_lds16(gr + off + lane_off, (char*)s_density + off);
    }
    #pragma unroll
    for (int it = 0; it < 6; ++it) {          // 24 KB feature
        int off = (it * 4 + wv) * 1024;
        load_lds16(gf + off + lane_off, (char*)s_feat + off);
    }

    __syncthreads();   // drains vmcnt for the LDS-DMA loads

    // ---- compute: 4 rays per wave (two 32-lane segments x two chains) ----
    const int seg = ln >> 5;
    const int s   = ln & 31;
    const int rayLA = wv * 4 + seg;
    const int rayLB = wv * 4 + 2 + seg;

    const float4 dA = *(const float4*)&s_depth  [rayLA * N_PTS + 4 * s];
    const float4 rA = *(const float4*)&s_density[rayLA * N_PTS + 4 * s];
    const float4 dB = *(const float4*)&s_depth  [rayLB * N_PTS + 4 * s];
    const float4 rB = *(const float4*)&s_density[rayLB * N_PTS + 4 * s];
    const float4* fA = (const float4*)&s_feat[rayLA * N_PTS * FEAT] + 3 * s;
    const float4* fB = (const float4*)&s_feat[rayLB * N_PTS * FEAT] + 3 * s;
    const float4 fA0 = fA[0], fA1 = fA[1], fA2 = fA[2];
    const float4 fB0 = fB[0], fB1 = fB[1], fB2 = fB[2];

    float nxA = __shfl_down(dA.x, 1);
    float nxB = __shfl_down(dB.x, 1);
    const bool last = (s == 31);
    float tA0 = rA.x * (dA.y - dA.x);
    float tA1 = rA.y * (dA.z - dA.y);
    float tA2 = rA.z * (dA.w - dA.z);
    float tA3 = rA.w * (last ? FAR_DELTA : (nxA - dA.w));
    float tB0 = rB.x * (dB.y - dB.x);
    float tB1 = rB.y * (dB.z - dB.y);
    float tB2 = rB.z * (dB.w - dB.z);
    float tB3 = rB.w * (last ? FAR_DELTA : (nxB - dB.w));

    float pA = tA0 + tA1 + tA2 + tA3;
    float pB = tB0 + tB1 + tB2 + tB3;
    float eA = __shfl_up(pA, 1, 32);
    float eB = __shfl_up(pB, 1, 32);
    if (s == 0) { eA = 0.0f; eB = 0.0f; }
    #pragma unroll
    for (int off = 1; off < 32; off <<= 1) {
        float xA = __shfl_up(eA, off, 32);
        float xB = __shfl_up(eB, off, 32);
        if (s >= off) { eA += xA; eB += xB; }
    }

    float TA0 = __expf(-eA);
    float TA1 = __expf(-(eA + tA0));
    float TA2 = __expf(-(eA + tA0 + tA1));
    float TA3 = __expf(-(eA + tA0 + tA1 + tA2));
    float TA4 = __expf(-(eA + pA));
    float TB0 = __expf(-eB);
    float TB1 = __expf(-(eB + tB0));
    float TB2 = __expf(-(eB + tB0 + tB1));
    float TB3 = __expf(-(eB + tB0 + tB1 + tB2));
    float TB4 = __expf(-(eB + pB));
    float wA0 = TA0 - TA1, wA1 = TA1 - TA2, wA2 = TA2 - TA3, wA3 = TA3 - TA4;
    float wB0 = TB0 - TB1, wB1 = TB1 - TB2, wB2 = TB2 - TB3, wB3 = TB3 - TB4;

    float a0 = wA0 * fA0.x + wA1 * fA0.w + wA2 * fA1.z + wA3 * fA2.y;
    float a1 = wA0 * fA0.y + wA1 * fA1.x + wA2 * fA1.w + wA3 * fA2.z;
    float a2 = wA0 * fA0.z + wA1 * fA1.y + wA2 * fA2.x + wA3 * fA2.w;
    float a3 = wA0 * dA.x  + wA1 * dA.y  + wA2 * dA.z  + wA3 * dA.w;
    float b0 = wB0 * fB0.x + wB1 * fB0.w + wB2 * fB1.z + wB3 * fB2.y;
    float b1 = wB0 * fB0.y + wB1 * fB1.x + wB2 * fB1.w + wB3 * fB2.z;
    float b2 = wB0 * fB0.z + wB1 * fB1.y + wB2 * fB2.x + wB3 * fB2.w;
    float b3 = wB0 * dB.x  + wB1 * dB.y  + wB2 * dB.z  + wB3 * dB.w;

    #pragma unroll
    for (int off = 16; off > 0; off >>= 1) {
        a0 += __shfl_down(a0, off, 32);
        a1 += __shfl_down(a1, off, 32);
        a2 += __shfl_down(a2, off, 32);
        a3 += __shfl_down(a3, off, 32);
        b0 += __shfl_down(b0, off, 32);
        b1 += __shfl_down(b1, off, 32);
        b2 += __shfl_down(b2, off, 32);
        b3 += __shfl_down(b3, off, 32);
    }

    if (s == 0) {
        *(float4*)(out + (size_t)(base_ray + rayLA) * 4) = make_float4(a0, a1, a2, a3);
        *(float4*)(out + (size_t)(base_ray + rayLB) * 4) = make_float4(b0, b1, b2, b3);
    }
}

extern "C" void kernel_launch(void* const* d_in, const int* in_sizes, int n_in,
                              void* d_out, int out_size, void* d_ws, size_t ws_size,
                              hipStream_t stream) {
    const float* depth   = (const float*)d_in[0];
    const float* density = (const float*)d_in[1];
    const float* feature = (const float*)d_in[2];
    float* out = (float*)d_out;

    dim3 grid(N_RAYS / RAYS_PER_BLOCK);   // 4096 blocks, 16 rays each
    dim3 block(256);
    volrend_kernel<<<grid, block, 0, stream>>>(depth, density, feature, out);
}